// Round 4
// baseline (2347.910 us; speedup 1.0000x reference)
//
#include <hip/hip_runtime.h>

#define NV   50000
#define NR   5
#define NT   8
#define CIN  64
#define COUT 64
#define VPB  4
#define BARY (NR*NT*3)      // 120
#define RTOT 2560           // NR*NT*CIN  (GEMM K)
#define NCOL 512            // NT*COUT    (GEMM N)
#define KSTEP 32
#define NCHUNK 80           // RTOT/KSTEP
#define BT_CHUNK (NCOL*KSTEP)   // 16384 elems per chunk
#define BT_ELEMS (NCHUNK*BT_CHUNK)
#define BM   128
#define NBLK ((NV + BM - 1) / BM)   // 391

#define WL_BYTES 262144
#define WS_NEED  (WL_BYTES + 2u * BT_ELEMS * 2u)   // ~5.5 MB

typedef __bf16 bf16x8 __attribute__((ext_vector_type(8)));
typedef float  f32x4  __attribute__((ext_vector_type(4)));
typedef unsigned short ushort8 __attribute__((ext_vector_type(8)));

// ---------- K0: build rotation-unrolled B^T in bf16 hi/lo, chunk-major ----------
// layout: bt[rc][n][rk], n=(k*64+d), r=rc*32+rk=(i*8+j)*64+c
__global__ __launch_bounds__(256) void build_bt(
    const float* __restrict__ kern, unsigned short* __restrict__ bth,
    unsigned short* __restrict__ btl)
{
    int e  = blockIdx.x * 256 + threadIdx.x;
    int rk = e & 31;
    int n  = (e >> 5) & 511;
    int rc = e >> 14;            // 512*32 = 2^14
    int r  = rc * KSTEP + rk;
    int i  = r >> 9;
    int j  = (r >> 6) & 7;
    int c  = r & 63;
    int k  = n >> 6;
    int d  = n & 63;
    float kv = kern[((i * NT + ((j + k) & 7)) * CIN + c) * COUT + d];
    __bf16 h = (__bf16)kv;
    float hf = (float)h;
    __bf16 lo = (__bf16)(kv - hf);
    bth[e] = __builtin_bit_cast(unsigned short, h);
    btl[e] = __builtin_bit_cast(unsigned short, lo);
}

// ---------- main: fused pullback + bf16-split MFMA GEMM + argmax ----------
__global__ __launch_bounds__(512, 2) void geo_mfma(
    const float* __restrict__ signal,
    const float* __restrict__ bary_w,
    const int*   __restrict__ bary_idx,
    const unsigned short* __restrict__ bth,
    const unsigned short* __restrict__ btl,
    float* __restrict__ out,
    int*   __restrict__ wl)
{
    __shared__ __align__(16) unsigned short Ah[BM][KSTEP];    // 8 KB
    __shared__ __align__(16) unsigned short Al[BM][KSTEP];    // 8 KB
    __shared__ __align__(16) unsigned short Bh[NCOL][KSTEP];  // 32 KB
    __shared__ __align__(16) unsigned short Bl[NCOL][KSTEP];  // 32 KB

    const int tid  = threadIdx.x;
    const int lane = tid & 63;
    const int wid  = tid >> 6;
    const int wm   = wid & 1;          // 2 M-waves: 64 rows each
    const int wn   = wid >> 1;         // 4 N-waves: 128 cols each
    const int g    = lane >> 4;
    const int l15  = lane & 15;
    const int vbase = blockIdx.x * BM;

    f32x4 acc[4][8];
    {
        f32x4 z = {0.f, 0.f, 0.f, 0.f};
        #pragma unroll
        for (int mf = 0; mf < 4; ++mf)
            #pragma unroll
            for (int nf = 0; nf < 8; ++nf) acc[mf][nf] = z;
    }

    const int avl = tid >> 2;          // vertex slot for A staging
    const int acq = (tid & 3) * 8;     // channel quad start

    for (int rc = 0; rc < NCHUNK; ++rc) {
        // ======== stage phase ========
        {   // A: pullback x[v, i, j, c0+acq .. +8) -> bf16 hi/lo
            const int i  = rc >> 4;
            const int j  = (rc >> 1) & 7;
            const int c0 = (rc & 1) * 32;
            const int v  = vbase + avl;
            float xv[8];
            if (v < NV) {
                const int base = v * BARY + (i * NT + j) * 3;
                const float w0 = bary_w[base + 0];
                const float w1 = bary_w[base + 1];
                const float w2 = bary_w[base + 2];
                const int   i0 = bary_idx[base + 0];
                const int   i1 = bary_idx[base + 1];
                const int   i2 = bary_idx[base + 2];
                const float4* s0 = (const float4*)(signal + i0 * CIN + c0 + acq);
                const float4* s1 = (const float4*)(signal + i1 * CIN + c0 + acq);
                const float4* s2 = (const float4*)(signal + i2 * CIN + c0 + acq);
                float4 p0 = s0[0], p1 = s0[1];
                float4 q0 = s1[0], q1 = s1[1];
                float4 r0 = s2[0], r1 = s2[1];
                xv[0] = w0*p0.x + w1*q0.x + w2*r0.x;
                xv[1] = w0*p0.y + w1*q0.y + w2*r0.y;
                xv[2] = w0*p0.z + w1*q0.z + w2*r0.z;
                xv[3] = w0*p0.w + w1*q0.w + w2*r0.w;
                xv[4] = w0*p1.x + w1*q1.x + w2*r1.x;
                xv[5] = w0*p1.y + w1*q1.y + w2*r1.y;
                xv[6] = w0*p1.z + w1*q1.z + w2*r1.z;
                xv[7] = w0*p1.w + w1*q1.w + w2*r1.w;
            } else {
                #pragma unroll
                for (int e = 0; e < 8; ++e) xv[e] = 0.f;
            }
            ushort8 hv, lv;
            #pragma unroll
            for (int e = 0; e < 8; ++e) {
                __bf16 h  = (__bf16)xv[e];
                float  hf = (float)h;
                __bf16 lo = (__bf16)(xv[e] - hf);
                hv[e] = __builtin_bit_cast(unsigned short, h);
                lv[e] = __builtin_bit_cast(unsigned short, lo);
            }
            *(ushort8*)&Ah[avl][acq] = hv;
            *(ushort8*)&Al[avl][acq] = lv;
        }
        {   // B: linear 32 KB x2 copy from ws (chunk-major, fully coalesced)
            const uint4* gh = (const uint4*)(bth + rc * BT_CHUNK);
            const uint4* gl = (const uint4*)(btl + rc * BT_CHUNK);
            uint4* lh = (uint4*)&Bh[0][0];
            uint4* ll = (uint4*)&Bl[0][0];
            #pragma unroll
            for (int p = 0; p < 4; ++p) {
                lh[tid + p * 512] = gh[tid + p * 512];
                ll[tid + p * 512] = gl[tid + p * 512];
            }
        }
        __syncthreads();

        // ======== compute phase ========
        bf16x8 ah[4], al[4];
        #pragma unroll
        for (int mf = 0; mf < 4; ++mf) {
            const int row = wm * 64 + mf * 16 + l15;
            ah[mf] = *(const bf16x8*)&Ah[row][g * 8];
            al[mf] = *(const bf16x8*)&Al[row][g * 8];
        }
        #pragma unroll
        for (int nf = 0; nf < 8; ++nf) {
            const int col = wn * 128 + nf * 16 + l15;
            bf16x8 bh = *(const bf16x8*)&Bh[col][g * 8];
            bf16x8 bl = *(const bf16x8*)&Bl[col][g * 8];
            #pragma unroll
            for (int mf = 0; mf < 4; ++mf) {
                acc[mf][nf] = __builtin_amdgcn_mfma_f32_16x16x32_bf16(ah[mf], bh, acc[mf][nf], 0, 0, 0);
                acc[mf][nf] = __builtin_amdgcn_mfma_f32_16x16x32_bf16(ah[mf], bl, acc[mf][nf], 0, 0, 0);
                acc[mf][nf] = __builtin_amdgcn_mfma_f32_16x16x32_bf16(al[mf], bh, acc[mf][nf], 0, 0, 0);
            }
        }
        __syncthreads();
    }

    // ======== epilogue: norms, argmax + gap flag, store ========
    // reuse A-tile LDS (free after last compute + barrier above)
    float* nrm   = (float*)&Ah[0][0];   // [BM][8] = 4 KB
    int*   besti = (int*)&Al[0][0];     // [BM]

    #pragma unroll
    for (int kbl = 0; kbl < 2; ++kbl) {
        float pn[4][4];
        #pragma unroll
        for (int mf = 0; mf < 4; ++mf)
            #pragma unroll
            for (int ri = 0; ri < 4; ++ri) {
                float s = 0.f;
                #pragma unroll
                for (int nf = kbl * 4; nf < kbl * 4 + 4; ++nf) {
                    float vv = acc[mf][nf][ri];
                    s = fmaf(vv, vv, s);
                }
                pn[mf][ri] = s;
            }
        #pragma unroll
        for (int off = 1; off < 16; off <<= 1)
            #pragma unroll
            for (int mf = 0; mf < 4; ++mf)
                #pragma unroll
                for (int ri = 0; ri < 4; ++ri)
                    pn[mf][ri] += __shfl_xor(pn[mf][ri], off);
        if (l15 == 0) {
            #pragma unroll
            for (int mf = 0; mf < 4; ++mf)
                #pragma unroll
                for (int ri = 0; ri < 4; ++ri) {
                    int vl = wm * 64 + mf * 16 + g * 4 + ri;
                    nrm[vl * 8 + wn * 2 + kbl] = pn[mf][ri];
                }
        }
    }
    __syncthreads();

    if (tid < BM) {
        const int v = vbase + tid;
        float bn = nrm[tid * 8 + 0];
        float sec = -1e30f;
        int best = 0;
        #pragma unroll
        for (int k = 1; k < 8; ++k) {
            float nv = nrm[tid * 8 + k];
            if (nv > bn)       { sec = bn; bn = nv; best = k; }
            else if (nv > sec) { sec = nv; }
        }
        const bool flag = (bn - sec) <= (2e-2f + 5e-4f * bn);
        besti[tid] = flag ? -1 : best;
        if (flag && v < NV) { int pos = atomicAdd(wl, 1); wl[1 + pos] = v; }
    }
    __syncthreads();

    #pragma unroll
    for (int mf = 0; mf < 4; ++mf)
        #pragma unroll
        for (int ri = 0; ri < 4; ++ri) {
            const int vl = wm * 64 + mf * 16 + g * 4 + ri;
            const int v  = vbase + vl;
            if (v >= NV) continue;
            const int b = besti[vl];
            if (b < 0 || (b >> 1) != wn) continue;
            const int kbl = b & 1;
            #pragma unroll
            for (int nf2 = 0; nf2 < 4; ++nf2) {
                const int nf = kbl * 4 + nf2;
                const int d  = (nf & 3) * 16 + l15;
                out[v * COUT + d] = fmaxf(acc[mf][nf][ri], 0.0f);
            }
        }
}

// ---------- fp64 refine for flagged vertices (also full fallback) ----------
__global__ __launch_bounds__(256) void geo_refine_f64(
    const float* __restrict__ signal,
    const float* __restrict__ bary_w,
    const int*   __restrict__ bary_idx,
    const float* __restrict__ kern,
    float*       __restrict__ out,
    const int*   __restrict__ wl,
    int nall)
{
    __shared__ __align__(16) float xs[4][NR][CIN][NT];
    const int wave = threadIdx.x >> 6;
    const int lane = threadIdx.x & 63;
    const int count = wl ? wl[0] : nall;
    const int nw = gridDim.x * 4;

    for (int w = blockIdx.x * 4 + wave; w < count; w += nw) {
        const int v = wl ? wl[1 + w] : w;
        for (int ij = 0; ij < NR * NT; ++ij) {
            int i = ij >> 3, j = ij & 7;
            int base = v * BARY + ij * 3;
            float w0 = bary_w[base], w1 = bary_w[base+1], w2 = bary_w[base+2];
            int   i0 = bary_idx[base], i1 = bary_idx[base+1], i2 = bary_idx[base+2];
            xs[wave][i][lane][j] = w0 * signal[i0*CIN + lane]
                                 + w1 * signal[i1*CIN + lane]
                                 + w2 * signal[i2*CIN + lane];
        }
        double acc[NT];
        #pragma unroll
        for (int k = 0; k < NT; ++k) acc[k] = 0.0;
        for (int i = 0; i < NR; ++i) {
            const float* __restrict__ Ki = kern + i * (NT * CIN * COUT);
            for (int c = 0; c < CIN; ++c) {
                float4 xa = *reinterpret_cast<const float4*>(&xs[wave][i][c][0]);
                float4 xb = *reinterpret_cast<const float4*>(&xs[wave][i][c][4]);
                double x8[NT] = {(double)xa.x, (double)xa.y, (double)xa.z, (double)xa.w,
                                 (double)xb.x, (double)xb.y, (double)xb.z, (double)xb.w};
                #pragma unroll
                for (int m = 0; m < NT; ++m) {
                    double kv = (double)Ki[(m * CIN + c) * COUT + lane];
                    #pragma unroll
                    for (int k = 0; k < NT; ++k)
                        acc[k] = fma(x8[(m - k + NT) & (NT - 1)], kv, acc[k]);
                }
            }
        }
        double nk[NT];
        #pragma unroll
        for (int k = 0; k < NT; ++k) {
            double n = acc[k] * acc[k];
            #pragma unroll
            for (int off = 32; off >= 1; off >>= 1) n += __shfl_xor(n, off);
            nk[k] = n;
        }
        int best = 0; double bn = nk[0];
        #pragma unroll
        for (int k = 1; k < NT; ++k)
            if (nk[k] > bn) { bn = nk[k]; best = k; }
        double sel = acc[0];
        #pragma unroll
        for (int k = 1; k < NT; ++k) sel = (best == k) ? acc[k] : sel;
        out[v * COUT + lane] = fmaxf((float)sel, 0.0f);
    }
}

// ---------- round-3 fp32 two-pass fallback (ws too small for BT) ----------
__global__ __launch_bounds__(256) void geo_conv_f32(
    const float* __restrict__ signal,
    const float* __restrict__ bary_w,
    const int*   __restrict__ bary_idx,
    const float* __restrict__ kern,
    float*       __restrict__ out,
    int*         __restrict__ wl)
{
    __shared__ __align__(16) float xs[VPB][NR][CIN][NT];
    __shared__ float wsh[VPB][BARY];
    __shared__ int   ish[VPB][BARY];

    const int tid   = threadIdx.x;
    const int wave  = tid >> 6;
    const int lane  = tid & 63;
    const int vbase = blockIdx.x * VPB;

    for (int e = tid; e < VPB * BARY; e += 256) {
        int s = e / BARY, r = e - s * BARY;
        wsh[s][r] = bary_w[(vbase + s) * BARY + r];
        ish[s][r] = bary_idx[(vbase + s) * BARY + r];
    }
    __syncthreads();
    {
        const int s = wave;
        for (int ij = 0; ij < NR * NT; ++ij) {
            int i = ij >> 3, j = ij & 7;
            float w0 = wsh[s][ij*3], w1 = wsh[s][ij*3+1], w2 = wsh[s][ij*3+2];
            int   i0 = ish[s][ij*3], i1 = ish[s][ij*3+1], i2 = ish[s][ij*3+2];
            xs[s][i][lane][j] = w0 * signal[i0*CIN + lane]
                              + w1 * signal[i1*CIN + lane]
                              + w2 * signal[i2*CIN + lane];
        }
    }
    __syncthreads();

    float acc[NT];
    #pragma unroll
    for (int k = 0; k < NT; ++k) acc[k] = 0.0f;
    const int s = wave, d = lane;
    for (int i = 0; i < NR; ++i) {
        const float* __restrict__ Ki = kern + i * (NT * CIN * COUT);
        for (int c = 0; c < CIN; ++c) {
            float4 xa = *reinterpret_cast<const float4*>(&xs[s][i][c][0]);
            float4 xb = *reinterpret_cast<const float4*>(&xs[s][i][c][4]);
            float x8[NT] = {xa.x, xa.y, xa.z, xa.w, xb.x, xb.y, xb.z, xb.w};
            #pragma unroll
            for (int m = 0; m < NT; ++m) {
                float kv = Ki[(m * CIN + c) * COUT + d];
                #pragma unroll
                for (int k = 0; k < NT; ++k)
                    acc[k] = fmaf(x8[(m - k + NT) & (NT - 1)], kv, acc[k]);
            }
        }
    }
    double nk[NT];
    #pragma unroll
    for (int k = 0; k < NT; ++k) {
        double n = (double)acc[k] * (double)acc[k];
        #pragma unroll
        for (int off = 32; off >= 1; off >>= 1) n += __shfl_xor(n, off);
        nk[k] = n;
    }
    int best = 0; double bn = nk[0], sec = -1.0e300;
    #pragma unroll
    for (int k = 1; k < NT; ++k) {
        if (nk[k] > bn)       { sec = bn; bn = nk[k]; best = k; }
        else if (nk[k] > sec) { sec = nk[k]; }
    }
    const int v = vbase + s;
    if (bn - sec <= 4.0e-3 + 3.0e-5 * bn) {
        if (lane == 0) { int pos = atomicAdd(wl, 1); wl[1 + pos] = v; }
    } else {
        float sel = acc[0];
        #pragma unroll
        for (int k = 1; k < NT; ++k) sel = (best == k) ? acc[k] : sel;
        out[v * COUT + d] = fmaxf(sel, 0.0f);
    }
}

extern "C" void kernel_launch(void* const* d_in, const int* in_sizes, int n_in,
                              void* d_out, int out_size, void* d_ws, size_t ws_size,
                              hipStream_t stream) {
    const float* signal   = (const float*)d_in[0];
    const float* bary_w   = (const float*)d_in[1];
    const int*   bary_idx = (const int*)d_in[2];
    const float* kern     = (const float*)d_in[3];
    float* out = (float*)d_out;

    if (ws_size >= (size_t)WS_NEED) {
        int* wl = (int*)d_ws;
        unsigned short* bth = (unsigned short*)((char*)d_ws + WL_BYTES);
        unsigned short* btl = bth + BT_ELEMS;
        hipMemsetAsync(wl, 0, sizeof(int), stream);
        build_bt<<<dim3(BT_ELEMS / 256), dim3(256), 0, stream>>>(kern, bth, btl);
        geo_mfma<<<dim3(NBLK), dim3(512), 0, stream>>>(
            signal, bary_w, bary_idx, bth, btl, out, wl);
        geo_refine_f64<<<dim3(128), dim3(256), 0, stream>>>(
            signal, bary_w, bary_idx, kern, out, wl, 0);
    } else if (ws_size >= (size_t)(1 + NV) * sizeof(int)) {
        int* wl = (int*)d_ws;
        hipMemsetAsync(wl, 0, sizeof(int), stream);
        geo_conv_f32<<<dim3(NV / VPB), dim3(256), 0, stream>>>(
            signal, bary_w, bary_idx, kern, out, wl);
        geo_refine_f64<<<dim3(128), dim3(256), 0, stream>>>(
            signal, bary_w, bary_idx, kern, out, wl, 0);
    } else {
        geo_refine_f64<<<dim3(256), dim3(256), 0, stream>>>(
            signal, bary_w, bary_idx, kern, out, nullptr, NV);
    }
}

// Round 5
// 829.016 us; speedup vs baseline: 2.8322x; 2.8322x over previous
//
#include <hip/hip_runtime.h>

#define NV   50000
#define NR   5
#define NT   8
#define CIN  64
#define COUT 64
#define VPB  4
#define BARY (NR*NT*3)      // 120
#define RTOT 2560           // NR*NT*CIN  (GEMM K)
#define NCOL 512            // NT*COUT    (GEMM N)
#define KSTEP 32
#define NCHUNK 80           // RTOT/KSTEP
#define BT_CHUNK (NCOL*KSTEP)   // 16384 elems per chunk
#define BT_ELEMS (NCHUNK*BT_CHUNK)
#define BM   128
#define NBLK ((NV + BM - 1) / BM)   // 391

#define WL_BYTES 262144
#define WS_NEED  (WL_BYTES + 2u * BT_ELEMS * 2u)   // ~5.5 MB

typedef __bf16 bf16x8 __attribute__((ext_vector_type(8)));
typedef float  f32x4  __attribute__((ext_vector_type(4)));
typedef unsigned short ushort8 __attribute__((ext_vector_type(8)));

// ---------- K0: build rotation-unrolled B^T in bf16 hi/lo, chunk-major ----------
// layout: bt[rc][n][rk], n=(k*64+d), r=rc*32+rk=(i*8+j)*64+c
__global__ __launch_bounds__(256) void build_bt(
    const float* __restrict__ kern, unsigned short* __restrict__ bth,
    unsigned short* __restrict__ btl)
{
    int e  = blockIdx.x * 256 + threadIdx.x;
    int rk = e & 31;
    int n  = (e >> 5) & 511;
    int rc = e >> 14;            // 512*32 = 2^14
    int r  = rc * KSTEP + rk;
    int i  = r >> 9;
    int j  = (r >> 6) & 7;
    int c  = r & 63;
    int k  = n >> 6;
    int d  = n & 63;
    float kv = kern[((i * NT + ((j + k) & 7)) * CIN + c) * COUT + d];
    __bf16 h = (__bf16)kv;
    float hf = (float)h;
    __bf16 lo = (__bf16)(kv - hf);
    bth[e] = __builtin_bit_cast(unsigned short, h);
    btl[e] = __builtin_bit_cast(unsigned short, lo);
}

// ---------- main: fused pullback + bf16-split MFMA GEMM + argmax ----------
__global__ __launch_bounds__(512, 2) void geo_mfma(
    const float* __restrict__ signal,
    const float* __restrict__ bary_w,
    const int*   __restrict__ bary_idx,
    const unsigned short* __restrict__ bth,
    const unsigned short* __restrict__ btl,
    float* __restrict__ out,
    int*   __restrict__ wl)
{
    __shared__ __align__(16) unsigned short Ah[BM][KSTEP];    // 8 KB
    __shared__ __align__(16) unsigned short Al[BM][KSTEP];    // 8 KB
    __shared__ __align__(16) unsigned short Bh[NCOL][KSTEP];  // 32 KB
    __shared__ __align__(16) unsigned short Bl[NCOL][KSTEP];  // 32 KB

    const int tid  = threadIdx.x;
    const int lane = tid & 63;
    const int wid  = tid >> 6;
    const int wm   = wid & 1;          // 2 M-waves: 64 rows each
    const int wn   = wid >> 1;         // 4 N-waves: 128 cols each
    const int g    = lane >> 4;
    const int l15  = lane & 15;
    const int vbase = blockIdx.x * BM;

    f32x4 acc[4][8];
    {
        f32x4 z = {0.f, 0.f, 0.f, 0.f};
        #pragma unroll
        for (int mf = 0; mf < 4; ++mf)
            #pragma unroll
            for (int nf = 0; nf < 8; ++nf) acc[mf][nf] = z;
    }

    const int avl = tid >> 2;          // vertex slot for A staging
    const int acq = (tid & 3) * 8;     // channel quad start

    for (int rc = 0; rc < NCHUNK; ++rc) {
        // ======== stage phase ========
        {   // A: pullback x[v, i, j, c0+acq .. +8) -> bf16 hi/lo
            const int i  = rc >> 4;
            const int j  = (rc >> 1) & 7;
            const int c0 = (rc & 1) * 32;
            const int v  = vbase + avl;
            float xv[8];
            if (v < NV) {
                const int base = v * BARY + (i * NT + j) * 3;
                const float w0 = bary_w[base + 0];
                const float w1 = bary_w[base + 1];
                const float w2 = bary_w[base + 2];
                const int   i0 = bary_idx[base + 0];
                const int   i1 = bary_idx[base + 1];
                const int   i2 = bary_idx[base + 2];
                const float4* s0 = (const float4*)(signal + i0 * CIN + c0 + acq);
                const float4* s1 = (const float4*)(signal + i1 * CIN + c0 + acq);
                const float4* s2 = (const float4*)(signal + i2 * CIN + c0 + acq);
                float4 p0 = s0[0], p1 = s0[1];
                float4 q0 = s1[0], q1 = s1[1];
                float4 r0 = s2[0], r1 = s2[1];
                xv[0] = w0*p0.x + w1*q0.x + w2*r0.x;
                xv[1] = w0*p0.y + w1*q0.y + w2*r0.y;
                xv[2] = w0*p0.z + w1*q0.z + w2*r0.z;
                xv[3] = w0*p0.w + w1*q0.w + w2*r0.w;
                xv[4] = w0*p1.x + w1*q1.x + w2*r1.x;
                xv[5] = w0*p1.y + w1*q1.y + w2*r1.y;
                xv[6] = w0*p1.z + w1*q1.z + w2*r1.z;
                xv[7] = w0*p1.w + w1*q1.w + w2*r1.w;
            } else {
                #pragma unroll
                for (int e = 0; e < 8; ++e) xv[e] = 0.f;
            }
            ushort8 hv, lv;
            #pragma unroll
            for (int e = 0; e < 8; ++e) {
                __bf16 h  = (__bf16)xv[e];
                float  hf = (float)h;
                __bf16 lo = (__bf16)(xv[e] - hf);
                hv[e] = __builtin_bit_cast(unsigned short, h);
                lv[e] = __builtin_bit_cast(unsigned short, lo);
            }
            *(ushort8*)&Ah[avl][acq] = hv;
            *(ushort8*)&Al[avl][acq] = lv;
        }
        {   // B: linear 32 KB x2 copy from ws (chunk-major, fully coalesced)
            const uint4* gh = (const uint4*)(bth + rc * BT_CHUNK);
            const uint4* gl = (const uint4*)(btl + rc * BT_CHUNK);
            uint4* lh = (uint4*)&Bh[0][0];
            uint4* ll = (uint4*)&Bl[0][0];
            #pragma unroll
            for (int p = 0; p < 4; ++p) {
                lh[tid + p * 512] = gh[tid + p * 512];
                ll[tid + p * 512] = gl[tid + p * 512];
            }
        }
        __syncthreads();

        // ======== compute phase ========
        bf16x8 ah[4], al[4];
        #pragma unroll
        for (int mf = 0; mf < 4; ++mf) {
            const int row = wm * 64 + mf * 16 + l15;
            ah[mf] = *(const bf16x8*)&Ah[row][g * 8];
            al[mf] = *(const bf16x8*)&Al[row][g * 8];
        }
        #pragma unroll
        for (int nf = 0; nf < 8; ++nf) {
            const int col = wn * 128 + nf * 16 + l15;
            bf16x8 bh = *(const bf16x8*)&Bh[col][g * 8];
            bf16x8 bl = *(const bf16x8*)&Bl[col][g * 8];
            #pragma unroll
            for (int mf = 0; mf < 4; ++mf) {
                acc[mf][nf] = __builtin_amdgcn_mfma_f32_16x16x32_bf16(ah[mf], bh, acc[mf][nf], 0, 0, 0);
                acc[mf][nf] = __builtin_amdgcn_mfma_f32_16x16x32_bf16(ah[mf], bl, acc[mf][nf], 0, 0, 0);
                acc[mf][nf] = __builtin_amdgcn_mfma_f32_16x16x32_bf16(al[mf], bh, acc[mf][nf], 0, 0, 0);
            }
        }
        __syncthreads();
    }

    // ======== epilogue: norms, argmax + gap flag, store ========
    // reuse A-tile LDS (free after last compute + barrier above)
    float* nrm   = (float*)&Ah[0][0];   // [BM][8] = 4 KB
    int*   besti = (int*)&Al[0][0];     // [BM]

    #pragma unroll
    for (int kbl = 0; kbl < 2; ++kbl) {
        float pn[4][4];
        #pragma unroll
        for (int mf = 0; mf < 4; ++mf)
            #pragma unroll
            for (int ri = 0; ri < 4; ++ri) {
                float s = 0.f;
                #pragma unroll
                for (int nf = kbl * 4; nf < kbl * 4 + 4; ++nf) {
                    float vv = acc[mf][nf][ri];
                    s = fmaf(vv, vv, s);
                }
                pn[mf][ri] = s;
            }
        #pragma unroll
        for (int off = 1; off < 16; off <<= 1)
            #pragma unroll
            for (int mf = 0; mf < 4; ++mf)
                #pragma unroll
                for (int ri = 0; ri < 4; ++ri)
                    pn[mf][ri] += __shfl_xor(pn[mf][ri], off);
        if (l15 == 0) {
            #pragma unroll
            for (int mf = 0; mf < 4; ++mf)
                #pragma unroll
                for (int ri = 0; ri < 4; ++ri) {
                    int vl = wm * 64 + mf * 16 + g * 4 + ri;
                    nrm[vl * 8 + wn * 2 + kbl] = pn[mf][ri];
                }
        }
    }
    __syncthreads();

    if (tid < BM) {
        const int v = vbase + tid;
        float bn = nrm[tid * 8 + 0];
        float sec = -1e30f;
        int best = 0;
        #pragma unroll
        for (int k = 1; k < 8; ++k) {
            float nv = nrm[tid * 8 + k];
            if (nv > bn)       { sec = bn; bn = nv; best = k; }
            else if (nv > sec) { sec = nv; }
        }
        const bool flag = (bn - sec) <= (2e-2f + 5e-4f * bn);
        besti[tid] = flag ? -1 : best;
        if (flag && v < NV) { int pos = atomicAdd(wl, 1); wl[1 + pos] = v; }
    }
    __syncthreads();

    // Final store: ALL acc indices compile-time (rule #20 — the round-4
    // version computed kbl = b&1 at runtime and indexed acc[mf][kbl*4+nf2],
    // demoting the whole accumulator to scratch: 8.1 GB of spill writes).
    #pragma unroll
    for (int mf = 0; mf < 4; ++mf)
        #pragma unroll
        for (int ri = 0; ri < 4; ++ri) {
            const int vl = wm * 64 + mf * 16 + g * 4 + ri;
            const int v  = vbase + vl;
            const int b  = (v < NV) ? besti[vl] : -1;
            const bool mine = (b >= 0) && ((b >> 1) == wn);
            #pragma unroll
            for (int nf = 0; nf < 8; ++nf) {
                // runtime condition, compile-time index — no scratch
                if (mine && ((nf >> 2) == (b & 1))) {
                    const int d = (nf & 3) * 16 + l15;
                    out[v * COUT + d] = fmaxf(acc[mf][nf][ri], 0.0f);
                }
            }
        }
}

// ---------- fp64 refine for flagged vertices (also full fallback) ----------
__global__ __launch_bounds__(256) void geo_refine_f64(
    const float* __restrict__ signal,
    const float* __restrict__ bary_w,
    const int*   __restrict__ bary_idx,
    const float* __restrict__ kern,
    float*       __restrict__ out,
    const int*   __restrict__ wl,
    int nall)
{
    __shared__ __align__(16) float xs[4][NR][CIN][NT];
    const int wave = threadIdx.x >> 6;
    const int lane = threadIdx.x & 63;
    const int count = wl ? wl[0] : nall;
    const int nw = gridDim.x * 4;

    for (int w = blockIdx.x * 4 + wave; w < count; w += nw) {
        const int v = wl ? wl[1 + w] : w;
        for (int ij = 0; ij < NR * NT; ++ij) {
            int i = ij >> 3, j = ij & 7;
            int base = v * BARY + ij * 3;
            float w0 = bary_w[base], w1 = bary_w[base+1], w2 = bary_w[base+2];
            int   i0 = bary_idx[base], i1 = bary_idx[base+1], i2 = bary_idx[base+2];
            xs[wave][i][lane][j] = w0 * signal[i0*CIN + lane]
                                 + w1 * signal[i1*CIN + lane]
                                 + w2 * signal[i2*CIN + lane];
        }
        double acc[NT];
        #pragma unroll
        for (int k = 0; k < NT; ++k) acc[k] = 0.0;
        for (int i = 0; i < NR; ++i) {
            const float* __restrict__ Ki = kern + i * (NT * CIN * COUT);
            for (int c = 0; c < CIN; ++c) {
                float4 xa = *reinterpret_cast<const float4*>(&xs[wave][i][c][0]);
                float4 xb = *reinterpret_cast<const float4*>(&xs[wave][i][c][4]);
                double x8[NT] = {(double)xa.x, (double)xa.y, (double)xa.z, (double)xa.w,
                                 (double)xb.x, (double)xb.y, (double)xb.z, (double)xb.w};
                #pragma unroll
                for (int m = 0; m < NT; ++m) {
                    double kv = (double)Ki[(m * CIN + c) * COUT + lane];
                    #pragma unroll
                    for (int k = 0; k < NT; ++k)
                        acc[k] = fma(x8[(m - k + NT) & (NT - 1)], kv, acc[k]);
                }
            }
        }
        double nk[NT];
        #pragma unroll
        for (int k = 0; k < NT; ++k) {
            double n = acc[k] * acc[k];
            #pragma unroll
            for (int off = 32; off >= 1; off >>= 1) n += __shfl_xor(n, off);
            nk[k] = n;
        }
        int best = 0; double bn = nk[0];
        #pragma unroll
        for (int k = 1; k < NT; ++k)
            if (nk[k] > bn) { bn = nk[k]; best = k; }
        double sel = acc[0];
        #pragma unroll
        for (int k = 1; k < NT; ++k) sel = (best == k) ? acc[k] : sel;
        out[v * COUT + lane] = fmaxf((float)sel, 0.0f);
    }
}

// ---------- round-3 fp32 two-pass fallback (ws too small for BT) ----------
__global__ __launch_bounds__(256) void geo_conv_f32(
    const float* __restrict__ signal,
    const float* __restrict__ bary_w,
    const int*   __restrict__ bary_idx,
    const float* __restrict__ kern,
    float*       __restrict__ out,
    int*         __restrict__ wl)
{
    __shared__ __align__(16) float xs[VPB][NR][CIN][NT];
    __shared__ float wsh[VPB][BARY];
    __shared__ int   ish[VPB][BARY];

    const int tid   = threadIdx.x;
    const int wave  = tid >> 6;
    const int lane  = tid & 63;
    const int vbase = blockIdx.x * VPB;

    for (int e = tid; e < VPB * BARY; e += 256) {
        int s = e / BARY, r = e - s * BARY;
        wsh[s][r] = bary_w[(vbase + s) * BARY + r];
        ish[s][r] = bary_idx[(vbase + s) * BARY + r];
    }
    __syncthreads();
    {
        const int s = wave;
        for (int ij = 0; ij < NR * NT; ++ij) {
            int i = ij >> 3, j = ij & 7;
            float w0 = wsh[s][ij*3], w1 = wsh[s][ij*3+1], w2 = wsh[s][ij*3+2];
            int   i0 = ish[s][ij*3], i1 = ish[s][ij*3+1], i2 = ish[s][ij*3+2];
            xs[s][i][lane][j] = w0 * signal[i0*CIN + lane]
                              + w1 * signal[i1*CIN + lane]
                              + w2 * signal[i2*CIN + lane];
        }
    }
    __syncthreads();

    float acc[NT];
    #pragma unroll
    for (int k = 0; k < NT; ++k) acc[k] = 0.0f;
    const int s = wave, d = lane;
    for (int i = 0; i < NR; ++i) {
        const float* __restrict__ Ki = kern + i * (NT * CIN * COUT);
        for (int c = 0; c < CIN; ++c) {
            float4 xa = *reinterpret_cast<const float4*>(&xs[s][i][c][0]);
            float4 xb = *reinterpret_cast<const float4*>(&xs[s][i][c][4]);
            float x8[NT] = {xa.x, xa.y, xa.z, xa.w, xb.x, xb.y, xb.z, xb.w};
            #pragma unroll
            for (int m = 0; m < NT; ++m) {
                float kv = Ki[(m * CIN + c) * COUT + d];
                #pragma unroll
                for (int k = 0; k < NT; ++k)
                    acc[k] = fmaf(x8[(m - k + NT) & (NT - 1)], kv, acc[k]);
            }
        }
    }
    double nk[NT];
    #pragma unroll
    for (int k = 0; k < NT; ++k) {
        double n = (double)acc[k] * (double)acc[k];
        #pragma unroll
        for (int off = 32; off >= 1; off >>= 1) n += __shfl_xor(n, off);
        nk[k] = n;
    }
    int best = 0; double bn = nk[0], sec = -1.0e300;
    #pragma unroll
    for (int k = 1; k < NT; ++k) {
        if (nk[k] > bn)       { sec = bn; bn = nk[k]; best = k; }
        else if (nk[k] > sec) { sec = nk[k]; }
    }
    const int v = vbase + s;
    if (bn - sec <= 4.0e-3 + 3.0e-5 * bn) {
        if (lane == 0) { int pos = atomicAdd(wl, 1); wl[1 + pos] = v; }
    } else {
        float sel = acc[0];
        #pragma unroll
        for (int k = 1; k < NT; ++k) sel = (best == k) ? acc[k] : sel;
        out[v * COUT + d] = fmaxf(sel, 0.0f);
    }
}

extern "C" void kernel_launch(void* const* d_in, const int* in_sizes, int n_in,
                              void* d_out, int out_size, void* d_ws, size_t ws_size,
                              hipStream_t stream) {
    const float* signal   = (const float*)d_in[0];
    const float* bary_w   = (const float*)d_in[1];
    const int*   bary_idx = (const int*)d_in[2];
    const float* kern     = (const float*)d_in[3];
    float* out = (float*)d_out;

    if (ws_size >= (size_t)WS_NEED) {
        int* wl = (int*)d_ws;
        unsigned short* bth = (unsigned short*)((char*)d_ws + WL_BYTES);
        unsigned short* btl = bth + BT_ELEMS;
        hipMemsetAsync(wl, 0, sizeof(int), stream);
        build_bt<<<dim3(BT_ELEMS / 256), dim3(256), 0, stream>>>(kern, bth, btl);
        geo_mfma<<<dim3(NBLK), dim3(512), 0, stream>>>(
            signal, bary_w, bary_idx, bth, btl, out, wl);
        geo_refine_f64<<<dim3(128), dim3(256), 0, stream>>>(
            signal, bary_w, bary_idx, kern, out, wl, 0);
    } else if (ws_size >= (size_t)(1 + NV) * sizeof(int)) {
        int* wl = (int*)d_ws;
        hipMemsetAsync(wl, 0, sizeof(int), stream);
        geo_conv_f32<<<dim3(NV / VPB), dim3(256), 0, stream>>>(
            signal, bary_w, bary_idx, kern, out, wl);
        geo_refine_f64<<<dim3(128), dim3(256), 0, stream>>>(
            signal, bary_w, bary_idx, kern, out, wl, 0);
    } else {
        geo_refine_f64<<<dim3(256), dim3(256), 0, stream>>>(
            signal, bary_w, bary_idx, kern, out, nullptr, NV);
    }
}

// Round 6
// 669.150 us; speedup vs baseline: 3.5088x; 1.2389x over previous
//
#include <hip/hip_runtime.h>

#define NV   50000
#define NR   5
#define NT   8
#define CIN  64
#define COUT 64
#define VPB  4
#define BARY (NR*NT*3)      // 120
#define RTOT 2560           // NR*NT*CIN  (GEMM K)
#define NCOL 512            // NT*COUT    (GEMM N)
#define KSTEP 32
#define NCHUNK 80           // RTOT/KSTEP
#define BT_CHUNK (NCOL*KSTEP)   // 16384 elems per chunk
#define BT_ELEMS (NCHUNK*BT_CHUNK)
#define BM2  64
#define NBLK2 ((NV + BM2 - 1) / BM2)   // 782

#define WL_BYTES 262144
#define WS_NEED  (WL_BYTES + 2u * BT_ELEMS * 2u)   // ~5.5 MB

typedef __bf16 bf16x8 __attribute__((ext_vector_type(8)));
typedef float  f32x4  __attribute__((ext_vector_type(4)));
typedef unsigned short ushort4v __attribute__((ext_vector_type(4)));

// ---------- K0: build rotation-unrolled B^T in bf16 hi/lo, chunk-major ----------
// layout: bt[rc][n][rk], n=(k*64+d), r=rc*32+rk=(i*8+j)*64+c
__global__ __launch_bounds__(256) void build_bt(
    const float* __restrict__ kern, unsigned short* __restrict__ bth,
    unsigned short* __restrict__ btl)
{
    int e  = blockIdx.x * 256 + threadIdx.x;
    int rk = e & 31;
    int n  = (e >> 5) & 511;
    int rc = e >> 14;
    int r  = rc * KSTEP + rk;
    int i  = r >> 9;
    int j  = (r >> 6) & 7;
    int c  = r & 63;
    int k  = n >> 6;
    int d  = n & 63;
    float kv = kern[((i * NT + ((j + k) & 7)) * CIN + c) * COUT + d];
    __bf16 h = (__bf16)kv;
    float hf = (float)h;
    __bf16 lo = (__bf16)(kv - hf);
    bth[e] = __builtin_bit_cast(unsigned short, h);
    btl[e] = __builtin_bit_cast(unsigned short, lo);
}

// ---------- main v2: BM=64, B direct-from-L2, A dbuf LDS, 1 barrier/chunk ----------
__global__ __launch_bounds__(512, 4) void geo_mfma2(
    const float* __restrict__ signal,
    const float* __restrict__ bary_w,
    const int*   __restrict__ bary_idx,
    const unsigned short* __restrict__ bth,
    const unsigned short* __restrict__ btl,
    float* __restrict__ out,
    int*   __restrict__ wl)
{
    // A tile, bank-friendly layout: [buf][k-octet][row][8 ch] (frag read = 16
    // consecutive 16B chunks across l15 -> conflict-free ds_read_b128)
    __shared__ __align__(16) unsigned short Ah[2][4][BM2][8];   // 8 KB
    __shared__ __align__(16) unsigned short Al[2][4][BM2][8];   // 8 KB
    __shared__ float nrm[BM2][NT];                              // 2 KB
    __shared__ int   besti[BM2];

    const int tid  = threadIdx.x;
    const int lane = tid & 63;
    const int wn   = tid >> 6;         // 8 N-waves; wave wn owns rotation k=wn
    const int g    = lane >> 4;
    const int l15  = lane & 15;
    const int vbase = blockIdx.x * BM2;

    // staging mapping: 512 threads = 64 vertices x 8 ch-quads
    const int vt  = tid >> 3;          // vertex slot 0..63
    const int cq  = tid & 7;           // ch quad 0..7 (32 ch per chunk)
    const int oct = cq >> 1;           // k-octet 0..3
    const int pos = (cq & 1) * 4;      // position within octet

    f32x4 acc[4][4];
    {
        f32x4 z = {0.f, 0.f, 0.f, 0.f};
        #pragma unroll
        for (int mf = 0; mf < 4; ++mf)
            #pragma unroll
            for (int nf = 0; nf < 4; ++nf) acc[mf][nf] = z;
    }

    auto STAGE = [&](int rc, int b) {
        const int ii = rc >> 4;
        const int jj = (rc >> 1) & 7;
        const int c0 = (rc & 1) * 32;
        const int v  = vbase + vt;
        float xv[4];
        if (v < NV) {
            const int base = v * BARY + (ii * NT + jj) * 3;
            const float w0 = bary_w[base + 0];
            const float w1 = bary_w[base + 1];
            const float w2 = bary_w[base + 2];
            const int   i0 = bary_idx[base + 0];
            const int   i1 = bary_idx[base + 1];
            const int   i2 = bary_idx[base + 2];
            const int   ch = c0 + cq * 4;
            const float4 p  = *(const float4*)(signal + i0 * CIN + ch);
            const float4 qv = *(const float4*)(signal + i1 * CIN + ch);
            const float4 rv = *(const float4*)(signal + i2 * CIN + ch);
            xv[0] = w0 * p.x + w1 * qv.x + w2 * rv.x;
            xv[1] = w0 * p.y + w1 * qv.y + w2 * rv.y;
            xv[2] = w0 * p.z + w1 * qv.z + w2 * rv.z;
            xv[3] = w0 * p.w + w1 * qv.w + w2 * rv.w;
        } else {
            #pragma unroll
            for (int e = 0; e < 4; ++e) xv[e] = 0.f;
        }
        ushort4v hv, lv;
        #pragma unroll
        for (int e = 0; e < 4; ++e) {
            __bf16 h  = (__bf16)xv[e];
            float  hf = (float)h;
            __bf16 lo = (__bf16)(xv[e] - hf);
            hv[e] = __builtin_bit_cast(unsigned short, h);
            lv[e] = __builtin_bit_cast(unsigned short, lo);
        }
        *(ushort4v*)&Ah[b][oct][vt][pos] = hv;
        *(ushort4v*)&Al[b][oct][vt][pos] = lv;
    };

    STAGE(0, 0);
    __syncthreads();

    for (int rc = 0; rc < NCHUNK; ++rc) {
        const int b = rc & 1;

        // A fragments: lane l holds A[row=l15][k = g*8 .. +8]
        bf16x8 ah[4], al[4];
        #pragma unroll
        for (int mf = 0; mf < 4; ++mf) {
            ah[mf] = *(const bf16x8*)&Ah[b][g][mf * 16 + l15][0];
            al[mf] = *(const bf16x8*)&Al[b][g][mf * 16 + l15][0];
        }

        // B fragments straight from global (L2-resident, 1 KB contiguous/wave)
        const unsigned short* __restrict__ bch = bth + rc * BT_CHUNK;
        const unsigned short* __restrict__ bcl = btl + rc * BT_CHUNK;
        #pragma unroll
        for (int nf = 0; nf < 4; ++nf) {
            const int col = wn * 64 + nf * 16 + l15;
            const bf16x8 bh = *(const bf16x8*)(bch + col * KSTEP + g * 8);
            const bf16x8 bl = *(const bf16x8*)(bcl + col * KSTEP + g * 8);
            #pragma unroll
            for (int mf = 0; mf < 4; ++mf) {
                acc[mf][nf] = __builtin_amdgcn_mfma_f32_16x16x32_bf16(ah[mf], bh, acc[mf][nf], 0, 0, 0);
                acc[mf][nf] = __builtin_amdgcn_mfma_f32_16x16x32_bf16(ah[mf], bl, acc[mf][nf], 0, 0, 0);
                acc[mf][nf] = __builtin_amdgcn_mfma_f32_16x16x32_bf16(al[mf], bh, acc[mf][nf], 0, 0, 0);
            }
        }

        if (rc + 1 < NCHUNK) STAGE(rc + 1, b ^ 1);   // writes other buffer
        __syncthreads();
    }

    // ---- epilogue: wave wn owns rotation wn; norms per row ----
    #pragma unroll
    for (int mf = 0; mf < 4; ++mf)
        #pragma unroll
        for (int ri = 0; ri < 4; ++ri) {
            float s = 0.f;
            #pragma unroll
            for (int nf = 0; nf < 4; ++nf) {
                float vv = acc[mf][nf][ri];
                s = fmaf(vv, vv, s);
            }
            #pragma unroll
            for (int off = 1; off < 16; off <<= 1)
                s += __shfl_xor(s, off);
            if (l15 == 0) nrm[mf * 16 + g * 4 + ri][wn] = s;
        }
    __syncthreads();

    if (tid < BM2) {
        const int v = vbase + tid;
        float bn = nrm[tid][0];
        float sec = -1e30f;
        int best = 0;
        #pragma unroll
        for (int k = 1; k < NT; ++k) {
            float nv = nrm[tid][k];
            if (nv > bn)       { sec = bn; bn = nv; best = k; }
            else if (nv > sec) { sec = nv; }
        }
        // my norm^2 err vs fp64 ~5e-4 worst-case; np ref == fp64 argmax
        // everywhere (round-2 evidence) -> >=9x margin at this threshold.
        const bool flag = (bn - sec) <= (2e-3f + 4e-5f * bn);
        besti[tid] = flag ? -1 : best;
        if (flag && v < NV) { int p = atomicAdd(wl, 1); wl[1 + p] = v; }
    }
    __syncthreads();

    #pragma unroll
    for (int mf = 0; mf < 4; ++mf)
        #pragma unroll
        for (int ri = 0; ri < 4; ++ri) {
            const int row = mf * 16 + g * 4 + ri;
            const int v   = vbase + row;
            const int bsel = (v < NV) ? besti[row] : -1;
            if (bsel == wn) {
                #pragma unroll
                for (int nf = 0; nf < 4; ++nf) {
                    const int d = nf * 16 + l15;
                    out[v * COUT + d] = fmaxf(acc[mf][nf][ri], 0.0f);
                }
            }
        }
}

// ---------- fp64 refine for flagged vertices (also full fallback) ----------
__global__ __launch_bounds__(256) void geo_refine_f64(
    const float* __restrict__ signal,
    const float* __restrict__ bary_w,
    const int*   __restrict__ bary_idx,
    const float* __restrict__ kern,
    float*       __restrict__ out,
    const int*   __restrict__ wl,
    int nall)
{
    __shared__ __align__(16) float xs[4][NR][CIN][NT];
    const int wave = threadIdx.x >> 6;
    const int lane = threadIdx.x & 63;
    const int count = wl ? wl[0] : nall;
    const int nw = gridDim.x * 4;

    for (int w = blockIdx.x * 4 + wave; w < count; w += nw) {
        const int v = wl ? wl[1 + w] : w;
        for (int ij = 0; ij < NR * NT; ++ij) {
            int i = ij >> 3, j = ij & 7;
            int base = v * BARY + ij * 3;
            float w0 = bary_w[base], w1 = bary_w[base+1], w2 = bary_w[base+2];
            int   i0 = bary_idx[base], i1 = bary_idx[base+1], i2 = bary_idx[base+2];
            xs[wave][i][lane][j] = w0 * signal[i0*CIN + lane]
                                 + w1 * signal[i1*CIN + lane]
                                 + w2 * signal[i2*CIN + lane];
        }
        double acc[NT];
        #pragma unroll
        for (int k = 0; k < NT; ++k) acc[k] = 0.0;
        for (int i = 0; i < NR; ++i) {
            const float* __restrict__ Ki = kern + i * (NT * CIN * COUT);
            for (int c = 0; c < CIN; ++c) {
                float4 xa = *reinterpret_cast<const float4*>(&xs[wave][i][c][0]);
                float4 xb = *reinterpret_cast<const float4*>(&xs[wave][i][c][4]);
                double x8[NT] = {(double)xa.x, (double)xa.y, (double)xa.z, (double)xa.w,
                                 (double)xb.x, (double)xb.y, (double)xb.z, (double)xb.w};
                #pragma unroll
                for (int m = 0; m < NT; ++m) {
                    double kv = (double)Ki[(m * CIN + c) * COUT + lane];
                    #pragma unroll
                    for (int k = 0; k < NT; ++k)
                        acc[k] = fma(x8[(m - k + NT) & (NT - 1)], kv, acc[k]);
                }
            }
        }
        double nk[NT];
        #pragma unroll
        for (int k = 0; k < NT; ++k) {
            double n = acc[k] * acc[k];
            #pragma unroll
            for (int off = 32; off >= 1; off >>= 1) n += __shfl_xor(n, off);
            nk[k] = n;
        }
        int best = 0; double bn = nk[0];
        #pragma unroll
        for (int k = 1; k < NT; ++k)
            if (nk[k] > bn) { bn = nk[k]; best = k; }
        double sel = acc[0];
        #pragma unroll
        for (int k = 1; k < NT; ++k) sel = (best == k) ? acc[k] : sel;
        out[v * COUT + lane] = fmaxf((float)sel, 0.0f);
    }
}

// ---------- round-3 fp32 two-pass fallback (ws too small for BT) ----------
__global__ __launch_bounds__(256) void geo_conv_f32(
    const float* __restrict__ signal,
    const float* __restrict__ bary_w,
    const int*   __restrict__ bary_idx,
    const float* __restrict__ kern,
    float*       __restrict__ out,
    int*         __restrict__ wl)
{
    __shared__ __align__(16) float xs[VPB][NR][CIN][NT];
    __shared__ float wsh[VPB][BARY];
    __shared__ int   ish[VPB][BARY];

    const int tid   = threadIdx.x;
    const int wave  = tid >> 6;
    const int lane  = tid & 63;
    const int vbase = blockIdx.x * VPB;

    for (int e = tid; e < VPB * BARY; e += 256) {
        int s = e / BARY, r = e - s * BARY;
        wsh[s][r] = bary_w[(vbase + s) * BARY + r];
        ish[s][r] = bary_idx[(vbase + s) * BARY + r];
    }
    __syncthreads();
    {
        const int s = wave;
        for (int ij = 0; ij < NR * NT; ++ij) {
            int i = ij >> 3, j = ij & 7;
            float w0 = wsh[s][ij*3], w1 = wsh[s][ij*3+1], w2 = wsh[s][ij*3+2];
            int   i0 = ish[s][ij*3], i1 = ish[s][ij*3+1], i2 = ish[s][ij*3+2];
            xs[s][i][lane][j] = w0 * signal[i0*CIN + lane]
                              + w1 * signal[i1*CIN + lane]
                              + w2 * signal[i2*CIN + lane];
        }
    }
    __syncthreads();

    float acc[NT];
    #pragma unroll
    for (int k = 0; k < NT; ++k) acc[k] = 0.0f;
    const int s = wave, d = lane;
    for (int i = 0; i < NR; ++i) {
        const float* __restrict__ Ki = kern + i * (NT * CIN * COUT);
        for (int c = 0; c < CIN; ++c) {
            float4 xa = *reinterpret_cast<const float4*>(&xs[s][i][c][0]);
            float4 xb = *reinterpret_cast<const float4*>(&xs[s][i][c][4]);
            float x8[NT] = {xa.x, xa.y, xa.z, xa.w, xb.x, xb.y, xb.z, xb.w};
            #pragma unroll
            for (int m = 0; m < NT; ++m) {
                float kv = Ki[(m * CIN + c) * COUT + d];
                #pragma unroll
                for (int k = 0; k < NT; ++k)
                    acc[k] = fmaf(x8[(m - k + NT) & (NT - 1)], kv, acc[k]);
            }
        }
    }
    double nk[NT];
    #pragma unroll
    for (int k = 0; k < NT; ++k) {
        double n = (double)acc[k] * (double)acc[k];
        #pragma unroll
        for (int off = 32; off >= 1; off >>= 1) n += __shfl_xor(n, off);
        nk[k] = n;
    }
    int best = 0; double bn = nk[0], sec = -1.0e300;
    #pragma unroll
    for (int k = 1; k < NT; ++k) {
        if (nk[k] > bn)       { sec = bn; bn = nk[k]; best = k; }
        else if (nk[k] > sec) { sec = nk[k]; }
    }
    const int v = vbase + s;
    if (bn - sec <= 4.0e-3 + 3.0e-5 * bn) {
        if (lane == 0) { int pos = atomicAdd(wl, 1); wl[1 + pos] = v; }
    } else {
        float sel = acc[0];
        #pragma unroll
        for (int k = 1; k < NT; ++k) sel = (best == k) ? acc[k] : sel;
        out[v * COUT + d] = fmaxf(sel, 0.0f);
    }
}

extern "C" void kernel_launch(void* const* d_in, const int* in_sizes, int n_in,
                              void* d_out, int out_size, void* d_ws, size_t ws_size,
                              hipStream_t stream) {
    const float* signal   = (const float*)d_in[0];
    const float* bary_w   = (const float*)d_in[1];
    const int*   bary_idx = (const int*)d_in[2];
    const float* kern     = (const float*)d_in[3];
    float* out = (float*)d_out;

    if (ws_size >= (size_t)WS_NEED) {
        int* wl = (int*)d_ws;
        unsigned short* bth = (unsigned short*)((char*)d_ws + WL_BYTES);
        unsigned short* btl = bth + BT_ELEMS;
        hipMemsetAsync(wl, 0, sizeof(int), stream);
        build_bt<<<dim3(BT_ELEMS / 256), dim3(256), 0, stream>>>(kern, bth, btl);
        geo_mfma2<<<dim3(NBLK2), dim3(512), 0, stream>>>(
            signal, bary_w, bary_idx, bth, btl, out, wl);
        geo_refine_f64<<<dim3(128), dim3(256), 0, stream>>>(
            signal, bary_w, bary_idx, kern, out, wl, 0);
    } else if (ws_size >= (size_t)(1 + NV) * sizeof(int)) {
        int* wl = (int*)d_ws;
        hipMemsetAsync(wl, 0, sizeof(int), stream);
        geo_conv_f32<<<dim3(NV / VPB), dim3(256), 0, stream>>>(
            signal, bary_w, bary_idx, kern, out, wl);
        geo_refine_f64<<<dim3(128), dim3(256), 0, stream>>>(
            signal, bary_w, bary_idx, kern, out, wl, 0);
    } else {
        geo_refine_f64<<<dim3(256), dim3(256), 0, stream>>>(
            signal, bary_w, bary_idx, kern, out, nullptr, NV);
    }
}